// Round 1
// baseline (4717.423 us; speedup 1.0000x reference)
//
#include <hip/hip_runtime.h>
#include <math.h>

#define N_ 4096
#define V_ 4
#define C_ 256

// ---------------- workspace layout (float offsets) ----------------
static const size_t OFF_DN    = 0;                       // 4*4096*256
static const size_t OFF_R     = OFF_DN   + (size_t)V_*N_*C_;   // 4*4096*256
static const size_t OFF_RELWT = OFF_R    + (size_t)V_*N_*C_;   // 16*256
static const size_t OFF_RMAX  = OFF_RELWT + 16*C_;             // 4096
static const size_t OFF_RSUM  = OFF_RMAX + N_;
static const size_t OFF_RARG  = OFF_RSUM + N_;                 // int
static const size_t OFF_CMAX  = OFF_RARG + N_;
static const size_t OFF_CSUM  = OFF_CMAX + N_;
static const size_t OFF_CARG  = OFF_CSUM + N_;                 // int
static const size_t OFF_CPMAX = OFF_CARG + N_;                 // 16*4096
static const size_t OFF_CPSUM = OFF_CPMAX + 16*(size_t)N_;
static const size_t OFF_CPARG = OFF_CPSUM + 16*(size_t)N_;     // int
static const size_t OFF_MUT0  = OFF_CPARG + 16*(size_t)N_;     // int 4096
static const size_t OFF_MUT1  = OFF_MUT0 + N_;                 // int 4096
static const size_t OFF_SQ    = OFF_MUT1 + N_;                 // 16 floats
static const size_t OFF_CNT   = OFF_SQ + 16;                   // 16 ints
static const size_t OFF_SIM   = ((OFF_CNT + 16 + 255) / 256) * 256; // 4096*4096

// ---------------- normalize: dn[v][n][c] = desc[n][v][c]/max(||.||,1e-12) ----
__global__ void normalize_k(const float* __restrict__ desc, float* __restrict__ dn) {
    int row = blockIdx.x;            // row = n*V + v
    int n = row >> 2, v = row & 3;
    const float* src = desc + (size_t)row * C_;
    float x = src[threadIdx.x];
    __shared__ float red[256];
    red[threadIdx.x] = x * x;
    __syncthreads();
    for (int s = 128; s > 0; s >>= 1) {
        if (threadIdx.x < s) red[threadIdx.x] += red[threadIdx.x + s];
        __syncthreads();
    }
    float inv = 1.0f / fmaxf(sqrtf(red[0]), 1e-12f);
    dn[((size_t)v * N_ + n) * C_ + threadIdx.x] = x * inv;
}

// ---------------- R_v = dn_v @ W_rec (all v) ----------------
__global__ void rmatmul_k(const float* __restrict__ dn, const float* __restrict__ Wrec,
                          float* __restrict__ R) {
    int v = blockIdx.y;
    int m0 = blockIdx.x * 16;
    __shared__ float rows[16][C_];
    const float* base = dn + ((size_t)v * N_ + m0) * C_;
    for (int r = 0; r < 16; ++r) rows[r][threadIdx.x] = base[(size_t)r * C_ + threadIdx.x];
    __syncthreads();
    float acc[16];
#pragma unroll
    for (int r = 0; r < 16; ++r) acc[r] = 0.f;
    int c = threadIdx.x;
    for (int k = 0; k < C_; ++k) {
        float w = Wrec[(size_t)k * C_ + c];
#pragma unroll
        for (int r = 0; r < 16; ++r) acc[r] += rows[r][k] * w;
    }
    float* outp = R + ((size_t)v * N_ + m0) * C_ + c;
    for (int r = 0; r < 16; ++r) outp[(size_t)r * C_] = acc[r];
}

// ---------------- relWT[p][c] for ordered pair p = i*4+j ----------------
__global__ void relwt_k(const float* __restrict__ T, const float* __restrict__ WT,
                        float* __restrict__ relwt) {
    int p = blockIdx.x; int i = p >> 2, j = p & 3;
    if (i == j) return;
    int c = threadIdx.x;
    float acc = 0.f;
    for (int k = 0; k < 16; ++k) acc += T[i * 16 + k] * WT[(size_t)k * C_ + c];
    for (int k = 0; k < 16; ++k) acc += T[j * 16 + k] * WT[(size_t)(16 + k) * C_ + c];
    relwt[(size_t)p * C_ + c] = acc;
}

__global__ void zero_k(float* sq, int* cnt) {
    if (threadIdx.x < 16) { sq[threadIdx.x] = 0.f; cnt[threadIdx.x] = 0; }
}

// ---------------- sim = A @ B^T (A,B: N x C row-major) ----------------
__global__ __launch_bounds__(256) void gemm_nt_k(const float* __restrict__ A,
                                                 const float* __restrict__ B,
                                                 float* __restrict__ S) {
    __shared__ float As[64][33];
    __shared__ float Bs[64][33];
    int m0 = blockIdx.y * 64, n0 = blockIdx.x * 64;
    int tid = threadIdx.x;
    int tx = tid & 15, ty = tid >> 4;
    int lr = tid >> 2;            // 0..63
    int lk = (tid & 3) * 4;       // 0,4,8,12
    float acc[4][4] = {};
    for (int k0 = 0; k0 < C_; k0 += 32) {
#pragma unroll
        for (int q = 0; q < 2; ++q) {
            int kk = q * 16 + lk;
            float4 av = *(const float4*)(A + (size_t)(m0 + lr) * C_ + k0 + kk);
            float4 bv = *(const float4*)(B + (size_t)(n0 + lr) * C_ + k0 + kk);
            As[lr][kk + 0] = av.x; As[lr][kk + 1] = av.y; As[lr][kk + 2] = av.z; As[lr][kk + 3] = av.w;
            Bs[lr][kk + 0] = bv.x; Bs[lr][kk + 1] = bv.y; Bs[lr][kk + 2] = bv.z; Bs[lr][kk + 3] = bv.w;
        }
        __syncthreads();
#pragma unroll
        for (int k = 0; k < 32; ++k) {
            float a[4], b[4];
#pragma unroll
            for (int i = 0; i < 4; ++i) a[i] = As[ty * 4 + i][k];
#pragma unroll
            for (int j = 0; j < 4; ++j) b[j] = Bs[tx * 4 + j][k];
#pragma unroll
            for (int i = 0; i < 4; ++i)
#pragma unroll
                for (int j = 0; j < 4; ++j) acc[i][j] += a[i] * b[j];
        }
        __syncthreads();
    }
#pragma unroll
    for (int i = 0; i < 4; ++i) {
        float4 w = make_float4(acc[i][0], acc[i][1], acc[i][2], acc[i][3]);
        *(float4*)(S + (size_t)(m0 + ty * 4 + i) * N_ + n0 + tx * 4) = w;
    }
}

// ---------------- row stats: max, argmax(first), sum exp(v-max) ----------------
__global__ void rowstats_k(const float* __restrict__ S, float* __restrict__ rmax,
                           float* __restrict__ rsum, int* __restrict__ rarg) {
    int m = blockIdx.x;
    const float* row = S + (size_t)m * N_;
    int tid = threadIdx.x;
    float mx = -INFINITY, sum = 0.f; int arg = 0;
    for (int c = tid; c < N_; c += 256) {
        float v = row[c];
        if (v > mx) { sum = sum * __expf(mx - v) + 1.f; mx = v; arg = c; }
        else sum += __expf(v - mx);
    }
    __shared__ float smx[256], ssum[256];
    __shared__ int sarg[256];
    smx[tid] = mx; ssum[tid] = sum; sarg[tid] = arg;
    __syncthreads();
    for (int s = 128; s > 0; s >>= 1) {
        if (tid < s) {
            float m1 = smx[tid], m2 = smx[tid + s];
            float s1 = ssum[tid], s2 = ssum[tid + s];
            int a1 = sarg[tid], a2 = sarg[tid + s];
            float M = fmaxf(m1, m2);
            ssum[tid] = s1 * __expf(m1 - M) + s2 * __expf(m2 - M);
            sarg[tid] = (m2 > m1) ? a2 : ((m1 > m2) ? a1 : min(a1, a2));
            smx[tid] = M;
        }
        __syncthreads();
    }
    if (tid == 0) { rmax[m] = smx[0]; rsum[m] = ssum[0]; rarg[m] = sarg[0]; }
}

// ---------------- column stats pass 1: 16 row-segments x 16 col-groups ----------
__global__ void colstats1_k(const float* __restrict__ S, float* __restrict__ pmx,
                            float* __restrict__ psum, int* __restrict__ parg) {
    int seg = blockIdx.x >> 4;
    int cg  = blockIdx.x & 15;
    int col = cg * 256 + threadIdx.x;
    float mx = -INFINITY, sum = 0.f; int arg = 0;
    int r0 = seg * 256;
    for (int r = r0; r < r0 + 256; ++r) {
        float v = S[(size_t)r * N_ + col];
        if (v > mx) { sum = sum * __expf(mx - v) + 1.f; mx = v; arg = r; }
        else sum += __expf(v - mx);
    }
    pmx[(size_t)seg * N_ + col] = mx;
    psum[(size_t)seg * N_ + col] = sum;
    parg[(size_t)seg * N_ + col] = arg;
}

// ---------------- column stats pass 2: merge 16 segments in row order ----------
__global__ void colstats2_k(const float* __restrict__ pmx, const float* __restrict__ psum,
                            const int* __restrict__ parg, float* __restrict__ cmax,
                            float* __restrict__ csum, int* __restrict__ carg) {
    int col = blockIdx.x * 256 + threadIdx.x;
    float mx = pmx[col], sum = psum[col]; int arg = parg[col];
    for (int seg = 1; seg < 16; ++seg) {
        float m2 = pmx[(size_t)seg * N_ + col];
        float s2 = psum[(size_t)seg * N_ + col];
        int a2 = parg[(size_t)seg * N_ + col];
        if (m2 > mx) { sum = sum * __expf(mx - m2) + s2; arg = a2; mx = m2; }
        else sum += s2 * __expf(m2 - mx);
    }
    cmax[col] = mx; csum[col] = sum; carg[col] = arg;
}

// ---------------- mutual masks + counts for both directions ----------------
__global__ void mutual_k(const int* __restrict__ rarg, const int* __restrict__ carg,
                         int* __restrict__ mut0, int* __restrict__ mut1,
                         int* __restrict__ cnt, int pid0, int pid1) {
    int d = blockIdx.x >> 4;
    int n = (blockIdx.x & 15) * 256 + threadIdx.x;
    int m;
    if (d == 0) { m = (carg[rarg[n]] == n) ? 1 : 0; mut0[n] = m; }
    else        { m = (rarg[carg[n]] == n) ? 1 : 0; mut1[n] = m; }
    __shared__ int red[256];
    red[threadIdx.x] = m;
    __syncthreads();
    for (int s = 128; s > 0; s >>= 1) {
        if (threadIdx.x < s) red[threadIdx.x] += red[threadIdx.x + s];
        __syncthreads();
    }
    if (threadIdx.x == 0) atomicAdd(&cnt[d == 0 ? pid0 : pid1], red[0]);
}

// ---------------- dir (i,j): softmax(sim,axis=1) @ sf_j, fused loss ----------
__global__ __launch_bounds__(256) void gemm2_nn_k(
    const float* __restrict__ S, const float* __restrict__ sf, int jview,
    const float* __restrict__ rmax, const float* __restrict__ rsum,
    const int* __restrict__ mut, const float* __restrict__ Ri,
    const float* __restrict__ relwt, float* __restrict__ sqAcc) {
    __shared__ float As[64][33];
    __shared__ float Bs[32][65];
    int m0 = blockIdx.y * 64, c0 = blockIdx.x * 64;
    int tid = threadIdx.x, tx = tid & 15, ty = tid >> 4;
    int alr = tid >> 2, alk = (tid & 3) * 4;
    int bkr = tid >> 4, bcq = (tid & 15) * 4;
    float rmax_l = rmax[m0 + alr];
    float acc[4][4] = {};
    for (int k0 = 0; k0 < N_; k0 += 32) {
#pragma unroll
        for (int q = 0; q < 2; ++q) {
            int kk = q * 16 + alk;
            float4 av = *(const float4*)(S + (size_t)(m0 + alr) * N_ + k0 + kk);
            As[alr][kk + 0] = __expf(av.x - rmax_l);
            As[alr][kk + 1] = __expf(av.y - rmax_l);
            As[alr][kk + 2] = __expf(av.z - rmax_l);
            As[alr][kk + 3] = __expf(av.w - rmax_l);
            int kr = q * 16 + bkr;
            float4 bv = *(const float4*)(sf + ((size_t)(k0 + kr) * V_ + jview) * C_ + c0 + bcq);
            Bs[kr][bcq + 0] = bv.x; Bs[kr][bcq + 1] = bv.y;
            Bs[kr][bcq + 2] = bv.z; Bs[kr][bcq + 3] = bv.w;
        }
        __syncthreads();
#pragma unroll
        for (int k = 0; k < 32; ++k) {
            float a[4], b[4];
#pragma unroll
            for (int i = 0; i < 4; ++i) a[i] = As[ty * 4 + i][k];
#pragma unroll
            for (int j = 0; j < 4; ++j) b[j] = Bs[k][tx * 4 + j];
#pragma unroll
            for (int i = 0; i < 4; ++i)
#pragma unroll
                for (int j = 0; j < 4; ++j) acc[i][j] += a[i] * b[j];
        }
        __syncthreads();
    }
    float local = 0.f;
#pragma unroll
    for (int i = 0; i < 4; ++i) {
        int m = m0 + ty * 4 + i;
        if (mut[m]) {
            float invZ = 1.f / rsum[m];
#pragma unroll
            for (int jj = 0; jj < 4; ++jj) {
                int c = c0 + tx * 4 + jj;
                float recon = Ri[(size_t)m * C_ + c] + relwt[c];
                float diff = recon - acc[i][jj] * invZ;
                local += diff * diff;
            }
        }
    }
    __shared__ float red[256];
    red[tid] = local;
    __syncthreads();
    for (int s = 128; s > 0; s >>= 1) {
        if (tid < s) red[tid] += red[tid + s];
        __syncthreads();
    }
    if (tid == 0) atomicAdd(sqAcc, red[0]);
}

// ---------------- dir (j,i): softmax(sim^T,axis=1) @ sf_i, fused loss --------
__global__ __launch_bounds__(256) void gemm2_tn_k(
    const float* __restrict__ S, const float* __restrict__ sf, int iview,
    const float* __restrict__ cmax, const float* __restrict__ csum,
    const int* __restrict__ mut, const float* __restrict__ Rj,
    const float* __restrict__ relwt, float* __restrict__ sqAcc) {
    __shared__ float As[32][65];   // [k(m)][n]
    __shared__ float Bs[32][65];   // [k][c]
    __shared__ float cmax_l[64];
    int n0 = blockIdx.y * 64, c0 = blockIdx.x * 64;
    int tid = threadIdx.x, tx = tid & 15, ty = tid >> 4;
    if (tid < 64) cmax_l[tid] = cmax[n0 + tid];
    __syncthreads();
    int akr = tid >> 4, anq = (tid & 15) * 4;
    float acc[4][4] = {};
    for (int k0 = 0; k0 < N_; k0 += 32) {
#pragma unroll
        for (int q = 0; q < 2; ++q) {
            int kr = q * 16 + akr;
            float4 av = *(const float4*)(S + (size_t)(k0 + kr) * N_ + n0 + anq);
            As[kr][anq + 0] = __expf(av.x - cmax_l[anq + 0]);
            As[kr][anq + 1] = __expf(av.y - cmax_l[anq + 1]);
            As[kr][anq + 2] = __expf(av.z - cmax_l[anq + 2]);
            As[kr][anq + 3] = __expf(av.w - cmax_l[anq + 3]);
            float4 bv = *(const float4*)(sf + ((size_t)(k0 + kr) * V_ + iview) * C_ + c0 + anq);
            Bs[kr][anq + 0] = bv.x; Bs[kr][anq + 1] = bv.y;
            Bs[kr][anq + 2] = bv.z; Bs[kr][anq + 3] = bv.w;
        }
        __syncthreads();
#pragma unroll
        for (int k = 0; k < 32; ++k) {
            float a[4], b[4];
#pragma unroll
            for (int i = 0; i < 4; ++i) a[i] = As[k][ty * 4 + i];
#pragma unroll
            for (int j = 0; j < 4; ++j) b[j] = Bs[k][tx * 4 + j];
#pragma unroll
            for (int i = 0; i < 4; ++i)
#pragma unroll
                for (int j = 0; j < 4; ++j) acc[i][j] += a[i] * b[j];
        }
        __syncthreads();
    }
    float local = 0.f;
#pragma unroll
    for (int i = 0; i < 4; ++i) {
        int n = n0 + ty * 4 + i;
        if (mut[n]) {
            float invZ = 1.f / csum[n];
#pragma unroll
            for (int jj = 0; jj < 4; ++jj) {
                int c = c0 + tx * 4 + jj;
                float recon = Rj[(size_t)n * C_ + c] + relwt[c];
                float diff = recon - acc[i][jj] * invZ;
                local += diff * diff;
            }
        }
    }
    __shared__ float red[256];
    red[tid] = local;
    __syncthreads();
    for (int s = 128; s > 0; s >>= 1) {
        if (tid < s) red[tid] += red[tid + s];
        __syncthreads();
    }
    if (tid == 0) atomicAdd(sqAcc, red[0]);
}

// ---------------- final scalar combine ----------------
__global__ void final_k(const float* __restrict__ sq, const int* __restrict__ cnt,
                        float* __restrict__ out) {
    if (threadIdx.x == 0 && blockIdx.x == 0) {
        float loss = 0.f, count = 0.f;
        for (int p = 0; p < 16; ++p) {
            int i = p >> 2, j = p & 3;
            if (i == j) continue;
            float ns = (float)cnt[p];
            if (ns > 0.f) { loss += sq[p] / fmaxf(ns * (float)C_, 1.0f); count += 1.f; }
        }
        out[0] = (count > 0.f) ? loss / count : 0.f;
    }
}

extern "C" void kernel_launch(void* const* d_in, const int* in_sizes, int n_in,
                              void* d_out, int out_size, void* d_ws, size_t ws_size,
                              hipStream_t stream) {
    const float* desc = (const float*)d_in[0];
    const float* sf   = (const float*)d_in[1];
    const float* T    = (const float*)d_in[2];
    const float* Wrec = (const float*)d_in[3];
    const float* WT   = (const float*)d_in[4];
    float* out = (float*)d_out;
    float* ws  = (float*)d_ws;

    float* dn    = ws + OFF_DN;
    float* R     = ws + OFF_R;
    float* relwt = ws + OFF_RELWT;
    float* rmax  = ws + OFF_RMAX;
    float* rsum  = ws + OFF_RSUM;
    int*   rarg  = (int*)(ws + OFF_RARG);
    float* cmax  = ws + OFF_CMAX;
    float* csum  = ws + OFF_CSUM;
    int*   carg  = (int*)(ws + OFF_CARG);
    float* cpmax = ws + OFF_CPMAX;
    float* cpsum = ws + OFF_CPSUM;
    int*   cparg = (int*)(ws + OFF_CPARG);
    int*   mut0  = (int*)(ws + OFF_MUT0);
    int*   mut1  = (int*)(ws + OFF_MUT1);
    float* pairSq = ws + OFF_SQ;
    int*   pairCnt = (int*)(ws + OFF_CNT);
    float* sim   = ws + OFF_SIM;

    normalize_k<<<N_ * V_, 256, 0, stream>>>(desc, dn);
    rmatmul_k<<<dim3(N_ / 16, V_), 256, 0, stream>>>(dn, Wrec, R);
    relwt_k<<<16, 256, 0, stream>>>(T, WT, relwt);
    zero_k<<<1, 64, 0, stream>>>(pairSq, pairCnt);

    for (int i = 0; i < V_; ++i) {
        for (int j = i + 1; j < V_; ++j) {
            const float* dni = dn + (size_t)i * N_ * C_;
            const float* dnj = dn + (size_t)j * N_ * C_;
            gemm_nt_k<<<dim3(64, 64), 256, 0, stream>>>(dni, dnj, sim);
            rowstats_k<<<N_, 256, 0, stream>>>(sim, rmax, rsum, rarg);
            colstats1_k<<<256, 256, 0, stream>>>(sim, cpmax, cpsum, cparg);
            colstats2_k<<<16, 256, 0, stream>>>(cpmax, cpsum, cparg, cmax, csum, carg);
            int pid0 = i * 4 + j, pid1 = j * 4 + i;
            mutual_k<<<32, 256, 0, stream>>>(rarg, carg, mut0, mut1, pairCnt, pid0, pid1);
            gemm2_nn_k<<<dim3(4, 64), 256, 0, stream>>>(
                sim, sf, j, rmax, rsum, mut0,
                R + (size_t)i * N_ * C_, relwt + (size_t)pid0 * C_, pairSq + pid0);
            gemm2_tn_k<<<dim3(4, 64), 256, 0, stream>>>(
                sim, sf, i, cmax, csum, mut1,
                R + (size_t)j * N_ * C_, relwt + (size_t)pid1 * C_, pairSq + pid1);
        }
    }
    final_k<<<1, 64, 0, stream>>>(pairSq, pairCnt, out);
}

// Round 2
// 1396.825 us; speedup vs baseline: 3.3772x; 3.3772x over previous
//
#include <hip/hip_runtime.h>
#include <math.h>

#define N_ 4096
#define V_ 4
#define C_ 256

typedef __attribute__((ext_vector_type(8))) short bf16x8;
typedef __attribute__((ext_vector_type(4))) float f32x4;

// ---------------- workspace byte offsets ----------------
#define OFF_DN     0ull
#define OFF_R      16777216ull
#define OFF_DNHI   33554432ull
#define OFF_DNLO   41943040ull
#define OFF_SFT    50331648ull
#define OFF_E      58720256ull
#define OFF_RPMAX  92274688ull
#define OFF_RPARG  93323264ull
#define OFF_RPSUM  94371840ull
#define OFF_CPMAX  95420416ull
#define OFF_CPARG  96468992ull
#define OFF_CPSUM  97517568ull
#define OFF_RARG   98566144ull
#define OFF_RSUM   98582528ull
#define OFF_CARG   98598912ull
#define OFF_CSUM   98615296ull
#define OFF_MUT0   98631680ull
#define OFF_MUT1   98648064ull
#define OFF_RELWT  98664448ull
#define OFF_SQ     98680832ull
#define OFF_CNT    98680896ull

__device__ __forceinline__ unsigned short f2bf(float x) {
    unsigned int u = __float_as_uint(x);
    u += 0x7fffu + ((u >> 16) & 1u);
    return (unsigned short)(u >> 16);
}
__device__ __forceinline__ float bf2f(unsigned short h) {
    return __uint_as_float(((unsigned int)h) << 16);
}
__device__ __forceinline__ f32x4 mfma16(bf16x8 a, bf16x8 b, f32x4 c) {
    return __builtin_amdgcn_mfma_f32_16x16x32_bf16(a, b, c, 0, 0, 0);
}

// ---- normalize + bf16 hi/lo split: dn[v][n][c] ----
__global__ void normalize_k(const float* __restrict__ desc, float* __restrict__ dn,
                            unsigned short* __restrict__ dnh, unsigned short* __restrict__ dnl) {
    int row = blockIdx.x;            // n*V + v
    int n = row >> 2, v = row & 3;
    int c = threadIdx.x;
    float x = desc[(size_t)row * C_ + c];
    __shared__ float red[256];
    red[c] = x * x;
    __syncthreads();
    for (int s = 128; s > 0; s >>= 1) {
        if (c < s) red[c] += red[c + s];
        __syncthreads();
    }
    float inv = 1.0f / fmaxf(sqrtf(red[0]), 1e-12f);
    float y = x * inv;
    size_t o = ((size_t)v * N_ + n) * C_ + c;
    dn[o] = y;
    unsigned short h = f2bf(y);
    dnh[o] = h;
    dnl[o] = f2bf(y - bf2f(h));
}

// ---- R_v = dn_v @ W_rec ----
__global__ void rmatmul_k(const float* __restrict__ dn, const float* __restrict__ Wrec,
                          float* __restrict__ R) {
    int v = blockIdx.y;
    int m0 = blockIdx.x * 16;
    __shared__ float rows[16][C_];
    const float* base = dn + ((size_t)v * N_ + m0) * C_;
    for (int r = 0; r < 16; ++r) rows[r][threadIdx.x] = base[(size_t)r * C_ + threadIdx.x];
    __syncthreads();
    float acc[16];
#pragma unroll
    for (int r = 0; r < 16; ++r) acc[r] = 0.f;
    int c = threadIdx.x;
    for (int k = 0; k < C_; ++k) {
        float w = Wrec[(size_t)k * C_ + c];
#pragma unroll
        for (int r = 0; r < 16; ++r) acc[r] += rows[r][k] * w;
    }
    float* outp = R + ((size_t)v * N_ + m0) * C_ + c;
    for (int r = 0; r < 16; ++r) outp[(size_t)r * C_] = acc[r];
}

// ---- relWT[p][c], p = i*4+j ----
__global__ void relwt_k(const float* __restrict__ T, const float* __restrict__ WT,
                        float* __restrict__ relwt) {
    int p = blockIdx.x; int i = p >> 2, j = p & 3;
    if (i == j) return;
    int c = threadIdx.x;
    float acc = 0.f;
    for (int k = 0; k < 16; ++k) acc += T[i * 16 + k] * WT[(size_t)k * C_ + c];
    for (int k = 0; k < 16; ++k) acc += T[j * 16 + k] * WT[(size_t)(16 + k) * C_ + c];
    relwt[(size_t)p * C_ + c] = acc;
}

// ---- sfT[v][c][n] = bf16(sf[n][v][c]) ----
__global__ void sfT_k(const float* __restrict__ sf, unsigned short* __restrict__ sfT) {
    __shared__ unsigned short Tt[64 * 72];   // [c][n], pitch 72
    int n0 = blockIdx.x * 64, c0 = blockIdx.y * 64, v = blockIdx.z;
    int t = threadIdx.x;
    int nr = t >> 2, cq = (t & 3) * 16;
    const float* src = sf + ((size_t)(n0 + nr) * V_ + v) * C_ + c0 + cq;
    for (int u = 0; u < 16; ++u) Tt[(cq + u) * 72 + nr] = f2bf(src[u]);
    __syncthreads();
    int cr = t >> 2, nq = (t & 3) * 16;
    unsigned short tmp[16] __attribute__((aligned(16)));
    for (int u = 0; u < 16; ++u) tmp[u] = Tt[cr * 72 + nq + u];
    unsigned short* dst = sfT + ((size_t)v * C_ + c0 + cr) * N_ + n0 + nq;
    *(uint4*)dst = *(const uint4*)tmp;
    *(uint4*)(dst + 8) = *(const uint4*)(tmp + 8);
}

__global__ void zero_k(float* sq, int* cnt) {
    if (threadIdx.x < 16) { sq[threadIdx.x] = 0.f; cnt[threadIdx.x] = 0; }
}

// ---- sim GEMM (split-bf16, 3 MFMA) + fused stats/E epilogue ----
__global__ __launch_bounds__(256) void sim_mfma_k(
    const unsigned short* __restrict__ Ahi, const unsigned short* __restrict__ Alo,
    const unsigned short* __restrict__ Bhi, const unsigned short* __restrict__ Blo,
    unsigned short* __restrict__ E,
    float* __restrict__ rpMax, int* __restrict__ rpArg, float* __restrict__ rpSum,
    float* __restrict__ cpMax, int* __restrict__ cpArg, float* __restrict__ cpSum) {
    __shared__ unsigned char smem[36864];
    __shared__ float sRedM[256];
    __shared__ int   sRedA[256];
    __shared__ float sRedS[256];
    unsigned short* sAh = (unsigned short*)smem;          // [64][72]
    unsigned short* sAl = sAh + 64 * 72;
    unsigned short* sBh = sAl + 64 * 72;
    unsigned short* sBl = sBh + 64 * 72;
    float* S = (float*)smem;                               // [64][65] (epilogue alias)

    int tid = threadIdx.x;
    int m0 = blockIdx.y * 64, n0 = blockIdx.x * 64;
    int w = tid >> 6, l = tid & 63;
    int wm = w & 1, wn = w >> 1;
    int mr = l & 15, q = l >> 4;

    f32x4 acc[2][2];
#pragma unroll
    for (int a = 0; a < 2; ++a)
#pragma unroll
        for (int b = 0; b < 2; ++b)
#pragma unroll
            for (int u = 0; u < 4; ++u) acc[a][b][u] = 0.f;

    int r = tid >> 2;
    int k8 = (tid & 3) * 8;

    for (int k0 = 0; k0 < C_; k0 += 64) {
        size_t ga = (size_t)(m0 + r) * C_ + k0 + k8;
        size_t gb = (size_t)(n0 + r) * C_ + k0 + k8;
        uint4 a0 = *(const uint4*)(Ahi + ga);
        uint4 a1 = *(const uint4*)(Ahi + ga + 32);
        uint4 a2 = *(const uint4*)(Alo + ga);
        uint4 a3 = *(const uint4*)(Alo + ga + 32);
        uint4 b0 = *(const uint4*)(Bhi + gb);
        uint4 b1 = *(const uint4*)(Bhi + gb + 32);
        uint4 b2 = *(const uint4*)(Blo + gb);
        uint4 b3 = *(const uint4*)(Blo + gb + 32);
        *(uint4*)(sAh + r * 72 + k8)      = a0;
        *(uint4*)(sAh + r * 72 + k8 + 32) = a1;
        *(uint4*)(sAl + r * 72 + k8)      = a2;
        *(uint4*)(sAl + r * 72 + k8 + 32) = a3;
        *(uint4*)(sBh + r * 72 + k8)      = b0;
        *(uint4*)(sBh + r * 72 + k8 + 32) = b1;
        *(uint4*)(sBl + r * 72 + k8)      = b2;
        *(uint4*)(sBl + r * 72 + k8 + 32) = b3;
        __syncthreads();
#pragma unroll
        for (int ks = 0; ks < 64; ks += 32) {
            bf16x8 ah[2], al[2], bh[2], bl[2];
#pragma unroll
            for (int ti = 0; ti < 2; ++ti) {
                int mrow = wm * 32 + ti * 16 + mr;
                ah[ti] = *(const bf16x8*)(sAh + mrow * 72 + ks + q * 8);
                al[ti] = *(const bf16x8*)(sAl + mrow * 72 + ks + q * 8);
            }
#pragma unroll
            for (int tj = 0; tj < 2; ++tj) {
                int nrow = wn * 32 + tj * 16 + mr;
                bh[tj] = *(const bf16x8*)(sBh + nrow * 72 + ks + q * 8);
                bl[tj] = *(const bf16x8*)(sBl + nrow * 72 + ks + q * 8);
            }
#pragma unroll
            for (int ti = 0; ti < 2; ++ti)
#pragma unroll
                for (int tj = 0; tj < 2; ++tj) {
                    acc[ti][tj] = mfma16(ah[ti], bh[tj], acc[ti][tj]);
                    acc[ti][tj] = mfma16(ah[ti], bl[tj], acc[ti][tj]);
                    acc[ti][tj] = mfma16(al[ti], bh[tj], acc[ti][tj]);
                }
        }
        __syncthreads();
    }

    // ---- epilogue: dump S tile to LDS (fp32) ----
#pragma unroll
    for (int ti = 0; ti < 2; ++ti)
#pragma unroll
        for (int tj = 0; tj < 2; ++tj)
#pragma unroll
            for (int rg = 0; rg < 4; ++rg)
                S[(wm * 32 + ti * 16 + q * 4 + rg) * 65 + wn * 32 + tj * 16 + mr] = acc[ti][tj][rg];
    __syncthreads();

    // row stats: 4 threads per row, 16 cols each (ascending -> first-occurrence argmax)
    {
        int rr = tid >> 2, q4 = tid & 3;
        float mx = -1e30f; int ag = 0; float sm = 0.f;
        for (int cc = 0; cc < 16; ++cc) {
            int c = q4 * 16 + cc;
            float v = S[rr * 65 + c];
            sm += __expf(v);
            if (v > mx) { mx = v; ag = c; }
        }
        sRedM[tid] = mx; sRedA[tid] = ag; sRedS[tid] = sm;
    }
    __syncthreads();
    if (tid < 64) {
        float mx = -1e30f; int ag = 0; float sm = 0.f;
        for (int qq = 0; qq < 4; ++qq) {
            float v = sRedM[tid * 4 + qq];
            if (v > mx) { mx = v; ag = sRedA[tid * 4 + qq]; }
            sm += sRedS[tid * 4 + qq];
        }
        size_t o = (size_t)blockIdx.x * N_ + m0 + tid;
        rpMax[o] = mx; rpArg[o] = n0 + ag; rpSum[o] = sm;
    }
    __syncthreads();
    // col stats
    {
        int cc = tid >> 2, q4 = tid & 3;
        float mx = -1e30f; int ag = 0; float sm = 0.f;
        for (int rr = 0; rr < 16; ++rr) {
            int rrr = q4 * 16 + rr;
            float v = S[rrr * 65 + cc];
            sm += __expf(v);
            if (v > mx) { mx = v; ag = rrr; }
        }
        sRedM[tid] = mx; sRedA[tid] = ag; sRedS[tid] = sm;
    }
    __syncthreads();
    if (tid < 64) {
        float mx = -1e30f; int ag = 0; float sm = 0.f;
        for (int qq = 0; qq < 4; ++qq) {
            float v = sRedM[tid * 4 + qq];
            if (v > mx) { mx = v; ag = sRedA[tid * 4 + qq]; }
            sm += sRedS[tid * 4 + qq];
        }
        size_t o = (size_t)blockIdx.y * N_ + n0 + tid;
        cpMax[o] = mx; cpArg[o] = m0 + ag; cpSum[o] = sm;
    }
    // E store (bf16 of exp(S))
    {
        int r2 = tid >> 2, cq = (tid & 3) * 16;
        unsigned short tmp[16] __attribute__((aligned(16)));
        for (int u = 0; u < 16; ++u) tmp[u] = f2bf(__expf(S[r2 * 65 + cq + u]));
        unsigned short* dst = E + (size_t)(m0 + r2) * N_ + n0 + cq;
        *(uint4*)dst = *(const uint4*)tmp;
        *(uint4*)(dst + 8) = *(const uint4*)(tmp + 8);
    }
}

// ---- merge 64 tile-partials per index ----
__global__ void merge_k(const float* __restrict__ pMax, const int* __restrict__ pArg,
                        const float* __restrict__ pSum, int* __restrict__ outArg,
                        float* __restrict__ outSum) {
    int m = blockIdx.x * 256 + threadIdx.x;
    float mx = -1e30f; int ag = 0; float sm = 0.f;
    for (int t = 0; t < 64; ++t) {
        float v = pMax[(size_t)t * N_ + m];
        if (v > mx) { mx = v; ag = pArg[(size_t)t * N_ + m]; }
        sm += pSum[(size_t)t * N_ + m];
    }
    outArg[m] = ag; outSum[m] = sm;
}

// ---- mutual masks + counts ----
__global__ void mutual_k(const int* __restrict__ rowArg, const int* __restrict__ colArg,
                         int* __restrict__ mut0, int* __restrict__ mut1,
                         int* __restrict__ cnt, int pid0, int pid1) {
    int d = blockIdx.x >> 4;
    int n = (blockIdx.x & 15) * 256 + threadIdx.x;
    int m;
    if (d == 0) { m = (colArg[rowArg[n]] == n) ? 1 : 0; mut0[n] = m; }
    else        { m = (rowArg[colArg[n]] == n) ? 1 : 0; mut1[n] = m; }
    __shared__ int red[256];
    red[threadIdx.x] = m;
    __syncthreads();
    for (int s = 128; s > 0; s >>= 1) {
        if (threadIdx.x < s) red[threadIdx.x] += red[threadIdx.x + s];
        __syncthreads();
    }
    if (threadIdx.x == 0) atomicAdd(&cnt[d == 0 ? pid0 : pid1], red[0]);
}

// ---- pass2 NT-GEMM (A row-major over k) + fused loss ----
__global__ __launch_bounds__(256) void p2_k(
    const unsigned short* __restrict__ A, const unsigned short* __restrict__ B,
    const float* __restrict__ sumE, const int* __restrict__ mutSel,
    const float* __restrict__ Rsel, const float* __restrict__ relwtP,
    float* __restrict__ sqAcc) {
    __shared__ unsigned short sA[64 * 72];
    __shared__ unsigned short sB[64 * 72];
    __shared__ float red[256];
    int tid = threadIdx.x;
    int c0 = blockIdx.x * 64, m0 = blockIdx.y * 64;
    int w = tid >> 6, l = tid & 63, wm = w & 1, wn = w >> 1;
    int mr = l & 15, q = l >> 4;
    f32x4 acc[2][2];
#pragma unroll
    for (int a = 0; a < 2; ++a)
#pragma unroll
        for (int b = 0; b < 2; ++b)
#pragma unroll
            for (int u = 0; u < 4; ++u) acc[a][b][u] = 0.f;
    int r = tid >> 2, k8 = (tid & 3) * 8;
    for (int k0 = 0; k0 < N_; k0 += 64) {
        uint4 a0 = *(const uint4*)(A + (size_t)(m0 + r) * N_ + k0 + k8);
        uint4 a1 = *(const uint4*)(A + (size_t)(m0 + r) * N_ + k0 + k8 + 32);
        uint4 b0 = *(const uint4*)(B + (size_t)(c0 + r) * N_ + k0 + k8);
        uint4 b1 = *(const uint4*)(B + (size_t)(c0 + r) * N_ + k0 + k8 + 32);
        *(uint4*)(sA + r * 72 + k8)      = a0;
        *(uint4*)(sA + r * 72 + k8 + 32) = a1;
        *(uint4*)(sB + r * 72 + k8)      = b0;
        *(uint4*)(sB + r * 72 + k8 + 32) = b1;
        __syncthreads();
#pragma unroll
        for (int ks = 0; ks < 64; ks += 32) {
            bf16x8 af[2], bfr[2];
#pragma unroll
            for (int ti = 0; ti < 2; ++ti)
                af[ti] = *(const bf16x8*)(sA + (wm * 32 + ti * 16 + mr) * 72 + ks + q * 8);
#pragma unroll
            for (int tj = 0; tj < 2; ++tj)
                bfr[tj] = *(const bf16x8*)(sB + (wn * 32 + tj * 16 + mr) * 72 + ks + q * 8);
#pragma unroll
            for (int ti = 0; ti < 2; ++ti)
#pragma unroll
                for (int tj = 0; tj < 2; ++tj)
                    acc[ti][tj] = mfma16(af[ti], bfr[tj], acc[ti][tj]);
        }
        __syncthreads();
    }
    float local = 0.f;
#pragma unroll
    for (int ti = 0; ti < 2; ++ti)
#pragma unroll
        for (int tj = 0; tj < 2; ++tj) {
            int c = c0 + wn * 32 + tj * 16 + mr;
#pragma unroll
            for (int rg = 0; rg < 4; ++rg) {
                int m = m0 + wm * 32 + ti * 16 + q * 4 + rg;
                if (mutSel[m]) {
                    float soft = acc[ti][tj][rg] / sumE[m];
                    float d = Rsel[(size_t)m * C_ + c] + relwtP[c] - soft;
                    local += d * d;
                }
            }
        }
    red[tid] = local;
    __syncthreads();
    for (int s = 128; s > 0; s >>= 1) {
        if (tid < s) red[tid] += red[tid + s];
        __syncthreads();
    }
    if (tid == 0) atomicAdd(sqAcc, red[0]);
}

// ---- pass2 with transposed-E A operand (LDS transpose staging) ----
__global__ __launch_bounds__(256) void p2t_k(
    const unsigned short* __restrict__ Eg, const unsigned short* __restrict__ B,
    const float* __restrict__ sumE, const int* __restrict__ mutSel,
    const float* __restrict__ Rsel, const float* __restrict__ relwtP,
    float* __restrict__ sqAcc) {
    __shared__ unsigned short sA[64 * 72];   // [n][r]
    __shared__ unsigned short sB[64 * 72];
    __shared__ float red[256];
    int tid = threadIdx.x;
    int c0 = blockIdx.x * 64, m0 = blockIdx.y * 64;   // m0 indexes E columns (n)
    int w = tid >> 6, l = tid & 63, wm = w & 1, wn = w >> 1;
    int mr = l & 15, q = l >> 4;
    f32x4 acc[2][2];
#pragma unroll
    for (int a = 0; a < 2; ++a)
#pragma unroll
        for (int b = 0; b < 2; ++b)
#pragma unroll
            for (int u = 0; u < 4; ++u) acc[a][b][u] = 0.f;
    int r = tid >> 2, k8 = (tid & 3) * 8;
    for (int k0 = 0; k0 < N_; k0 += 64) {
        uint4 a0 = *(const uint4*)(Eg + (size_t)(k0 + r) * N_ + m0 + k8);
        uint4 a1 = *(const uint4*)(Eg + (size_t)(k0 + r) * N_ + m0 + k8 + 32);
        uint4 b0 = *(const uint4*)(B + (size_t)(c0 + r) * N_ + k0 + k8);
        uint4 b1 = *(const uint4*)(B + (size_t)(c0 + r) * N_ + k0 + k8 + 32);
        unsigned short tmp[8] __attribute__((aligned(16)));
        *(uint4*)tmp = a0;
#pragma unroll
        for (int u = 0; u < 8; ++u) sA[(k8 + u) * 72 + r] = tmp[u];
        *(uint4*)tmp = a1;
#pragma unroll
        for (int u = 0; u < 8; ++u) sA[(k8 + 32 + u) * 72 + r] = tmp[u];
        *(uint4*)(sB + r * 72 + k8)      = b0;
        *(uint4*)(sB + r * 72 + k8 + 32) = b1;
        __syncthreads();
#pragma unroll
        for (int ks = 0; ks < 64; ks += 32) {
            bf16x8 af[2], bfr[2];
#pragma unroll
            for (int ti = 0; ti < 2; ++ti)
                af[ti] = *(const bf16x8*)(sA + (wm * 32 + ti * 16 + mr) * 72 + ks + q * 8);
#pragma unroll
            for (int tj = 0; tj < 2; ++tj)
                bfr[tj] = *(const bf16x8*)(sB + (wn * 32 + tj * 16 + mr) * 72 + ks + q * 8);
#pragma unroll
            for (int ti = 0; ti < 2; ++ti)
#pragma unroll
                for (int tj = 0; tj < 2; ++tj)
                    acc[ti][tj] = mfma16(af[ti], bfr[tj], acc[ti][tj]);
        }
        __syncthreads();
    }
    float local = 0.f;
#pragma unroll
    for (int ti = 0; ti < 2; ++ti)
#pragma unroll
        for (int tj = 0; tj < 2; ++tj) {
            int c = c0 + wn * 32 + tj * 16 + mr;
#pragma unroll
            for (int rg = 0; rg < 4; ++rg) {
                int m = m0 + wm * 32 + ti * 16 + q * 4 + rg;
                if (mutSel[m]) {
                    float soft = acc[ti][tj][rg] / sumE[m];
                    float d = Rsel[(size_t)m * C_ + c] + relwtP[c] - soft;
                    local += d * d;
                }
            }
        }
    red[tid] = local;
    __syncthreads();
    for (int s = 128; s > 0; s >>= 1) {
        if (tid < s) red[tid] += red[tid + s];
        __syncthreads();
    }
    if (tid == 0) atomicAdd(sqAcc, red[0]);
}

// ---- final scalar combine ----
__global__ void final_k(const float* __restrict__ sq, const int* __restrict__ cnt,
                        float* __restrict__ out) {
    if (threadIdx.x == 0 && blockIdx.x == 0) {
        float loss = 0.f, count = 0.f;
        for (int p = 0; p < 16; ++p) {
            int i = p >> 2, j = p & 3;
            if (i == j) continue;
            float ns = (float)cnt[p];
            if (ns > 0.f) { loss += sq[p] / fmaxf(ns * (float)C_, 1.0f); count += 1.f; }
        }
        out[0] = (count > 0.f) ? loss / count : 0.f;
    }
}

extern "C" void kernel_launch(void* const* d_in, const int* in_sizes, int n_in,
                              void* d_out, int out_size, void* d_ws, size_t ws_size,
                              hipStream_t stream) {
    const float* desc = (const float*)d_in[0];
    const float* sf   = (const float*)d_in[1];
    const float* T    = (const float*)d_in[2];
    const float* Wrec = (const float*)d_in[3];
    const float* WT   = (const float*)d_in[4];
    float* out = (float*)d_out;
    char* ws = (char*)d_ws;

    float*          dn    = (float*)(ws + OFF_DN);
    float*          R     = (float*)(ws + OFF_R);
    unsigned short* dnh   = (unsigned short*)(ws + OFF_DNHI);
    unsigned short* dnl   = (unsigned short*)(ws + OFF_DNLO);
    unsigned short* sfT   = (unsigned short*)(ws + OFF_SFT);
    unsigned short* E     = (unsigned short*)(ws + OFF_E);
    float* rpMax = (float*)(ws + OFF_RPMAX);
    int*   rpArg = (int*)(ws + OFF_RPARG);
    float* rpSum = (float*)(ws + OFF_RPSUM);
    float* cpMax = (float*)(ws + OFF_CPMAX);
    int*   cpArg = (int*)(ws + OFF_CPARG);
    float* cpSum = (float*)(ws + OFF_CPSUM);
    int*   rowArg = (int*)(ws + OFF_RARG);
    float* rowSum = (float*)(ws + OFF_RSUM);
    int*   colArg = (int*)(ws + OFF_CARG);
    float* colSum = (float*)(ws + OFF_CSUM);
    int*   mut0  = (int*)(ws + OFF_MUT0);
    int*   mut1  = (int*)(ws + OFF_MUT1);
    float* relwt = (float*)(ws + OFF_RELWT);
    float* pairSq = (float*)(ws + OFF_SQ);
    int*   pairCnt = (int*)(ws + OFF_CNT);

    normalize_k<<<N_ * V_, 256, 0, stream>>>(desc, dn, dnh, dnl);
    rmatmul_k<<<dim3(N_ / 16, V_), 256, 0, stream>>>(dn, Wrec, R);
    sfT_k<<<dim3(64, 4, 4), 256, 0, stream>>>(sf, sfT);
    relwt_k<<<16, 256, 0, stream>>>(T, WT, relwt);
    zero_k<<<1, 64, 0, stream>>>(pairSq, pairCnt);

    for (int i = 0; i < V_; ++i) {
        for (int j = i + 1; j < V_; ++j) {
            const unsigned short* Ahi = dnh + (size_t)i * N_ * C_;
            const unsigned short* Alo = dnl + (size_t)i * N_ * C_;
            const unsigned short* Bhi = dnh + (size_t)j * N_ * C_;
            const unsigned short* Blo = dnl + (size_t)j * N_ * C_;
            sim_mfma_k<<<dim3(64, 64), 256, 0, stream>>>(
                Ahi, Alo, Bhi, Blo, E, rpMax, rpArg, rpSum, cpMax, cpArg, cpSum);
            merge_k<<<16, 256, 0, stream>>>(rpMax, rpArg, rpSum, rowArg, rowSum);
            merge_k<<<16, 256, 0, stream>>>(cpMax, cpArg, cpSum, colArg, colSum);
            int pid0 = i * 4 + j, pid1 = j * 4 + i;
            mutual_k<<<32, 256, 0, stream>>>(rowArg, colArg, mut0, mut1, pairCnt, pid0, pid1);
            p2_k<<<dim3(4, 64), 256, 0, stream>>>(
                E, sfT + (size_t)j * C_ * N_, rowSum, mut0,
                R + (size_t)i * N_ * C_, relwt + (size_t)pid0 * C_, pairSq + pid0);
            p2t_k<<<dim3(4, 64), 256, 0, stream>>>(
                E, sfT + (size_t)i * C_ * N_, colSum, mut1,
                R + (size_t)j * N_ * C_, relwt + (size_t)pid1 * C_, pairSq + pid1);
        }
    }
    final_k<<<1, 64, 0, stream>>>(pairSq, pairCnt, out);
}

// Round 3
// 1378.252 us; speedup vs baseline: 3.4228x; 1.0135x over previous
//
#include <hip/hip_runtime.h>
#include <math.h>

#define N_ 4096
#define V_ 4
#define C_ 256

typedef __attribute__((ext_vector_type(8))) short bf16x8;
typedef __attribute__((ext_vector_type(4))) float f32x4;

// ---------------- workspace byte offsets ----------------
#define OFF_DN     0ull
#define OFF_R      16777216ull
#define OFF_DNHI   33554432ull
#define OFF_DNLO   41943040ull
#define OFF_SFT    50331648ull
#define OFF_E      58720256ull
#define OFF_ET     92274688ull
#define OFF_ACC    125829120ull     // 4 slices (dir*2+ks) x 4096 x 256 f32 = 16MB
#define OFF_RPMAX  142606336ull
#define OFF_RPARG  143654912ull
#define OFF_RPSUM  144703488ull
#define OFF_CPMAX  145752064ull
#define OFF_CPARG  146800640ull
#define OFF_CPSUM  147849216ull
#define OFF_RARG   148897792ull
#define OFF_RSUM   148914176ull
#define OFF_CARG   148930560ull
#define OFF_CSUM   148946944ull
#define OFF_RELWT  148963328ull
#define OFF_SQ     148979712ull
#define OFF_CNT    148979776ull

__device__ __forceinline__ unsigned short f2bf(float x) {
    unsigned int u = __float_as_uint(x);
    u += 0x7fffu + ((u >> 16) & 1u);
    return (unsigned short)(u >> 16);
}
__device__ __forceinline__ float bf2f(unsigned short h) {
    return __uint_as_float(((unsigned int)h) << 16);
}
__device__ __forceinline__ f32x4 mfma16(bf16x8 a, bf16x8 b, f32x4 c) {
    return __builtin_amdgcn_mfma_f32_16x16x32_bf16(a, b, c, 0, 0, 0);
}

// ---- normalize + bf16 hi/lo split: dn[v][n][c] ----
__global__ void normalize_k(const float* __restrict__ desc, float* __restrict__ dn,
                            unsigned short* __restrict__ dnh, unsigned short* __restrict__ dnl) {
    int row = blockIdx.x;            // n*V + v
    int n = row >> 2, v = row & 3;
    int c = threadIdx.x;
    float x = desc[(size_t)row * C_ + c];
    __shared__ float red[256];
    red[c] = x * x;
    __syncthreads();
    for (int s = 128; s > 0; s >>= 1) {
        if (c < s) red[c] += red[c + s];
        __syncthreads();
    }
    float inv = 1.0f / fmaxf(sqrtf(red[0]), 1e-12f);
    float y = x * inv;
    size_t o = ((size_t)v * N_ + n) * C_ + c;
    dn[o] = y;
    unsigned short h = f2bf(y);
    dnh[o] = h;
    dnl[o] = f2bf(y - bf2f(h));
}

// ---- R_v = dn_v @ W_rec ----
__global__ void rmatmul_k(const float* __restrict__ dn, const float* __restrict__ Wrec,
                          float* __restrict__ R) {
    int v = blockIdx.y;
    int m0 = blockIdx.x * 16;
    __shared__ float rows[16][C_];
    const float* base = dn + ((size_t)v * N_ + m0) * C_;
    for (int r = 0; r < 16; ++r) rows[r][threadIdx.x] = base[(size_t)r * C_ + threadIdx.x];
    __syncthreads();
    float acc[16];
#pragma unroll
    for (int r = 0; r < 16; ++r) acc[r] = 0.f;
    int c = threadIdx.x;
    for (int k = 0; k < C_; ++k) {
        float w = Wrec[(size_t)k * C_ + c];
#pragma unroll
        for (int r = 0; r < 16; ++r) acc[r] += rows[r][k] * w;
    }
    float* outp = R + ((size_t)v * N_ + m0) * C_ + c;
    for (int r = 0; r < 16; ++r) outp[(size_t)r * C_] = acc[r];
}

// ---- relWT[p][c], p = i*4+j ----
__global__ void relwt_k(const float* __restrict__ T, const float* __restrict__ WT,
                        float* __restrict__ relwt) {
    int p = blockIdx.x; int i = p >> 2, j = p & 3;
    if (i == j) return;
    int c = threadIdx.x;
    float acc = 0.f;
    for (int k = 0; k < 16; ++k) acc += T[i * 16 + k] * WT[(size_t)k * C_ + c];
    for (int k = 0; k < 16; ++k) acc += T[j * 16 + k] * WT[(size_t)(16 + k) * C_ + c];
    relwt[(size_t)p * C_ + c] = acc;
}

// ---- sfT[v][c][n] = bf16(sf[n][v][c]) ----
__global__ void sfT_k(const float* __restrict__ sf, unsigned short* __restrict__ sfT) {
    __shared__ unsigned short Tt[64 * 72];   // [c][n], pitch 72
    int n0 = blockIdx.x * 64, c0 = blockIdx.y * 64, v = blockIdx.z;
    int t = threadIdx.x;
    int nr = t >> 2, cq = (t & 3) * 16;
    const float* src = sf + ((size_t)(n0 + nr) * V_ + v) * C_ + c0 + cq;
    for (int u = 0; u < 16; ++u) Tt[(cq + u) * 72 + nr] = f2bf(src[u]);
    __syncthreads();
    int cr = t >> 2, nq = (t & 3) * 16;
    unsigned short tmp[16] __attribute__((aligned(16)));
    for (int u = 0; u < 16; ++u) tmp[u] = Tt[cr * 72 + nq + u];
    unsigned short* dst = sfT + ((size_t)v * C_ + c0 + cr) * N_ + n0 + nq;
    *(uint4*)dst = *(const uint4*)tmp;
    *(uint4*)(dst + 8) = *(const uint4*)(tmp + 8);
}

__global__ void zero_k(float* sq, int* cnt) {
    if (threadIdx.x < 16) { sq[threadIdx.x] = 0.f; cnt[threadIdx.x] = 0; }
}

// ---- sim GEMM (split-bf16, 3 MFMA) + fused stats/E/ET epilogue ----
__global__ __launch_bounds__(256) void sim_mfma_k(
    const unsigned short* __restrict__ Ahi, const unsigned short* __restrict__ Alo,
    const unsigned short* __restrict__ Bhi, const unsigned short* __restrict__ Blo,
    unsigned short* __restrict__ E, unsigned short* __restrict__ ET,
    float* __restrict__ rpMax, int* __restrict__ rpArg, float* __restrict__ rpSum,
    float* __restrict__ cpMax, int* __restrict__ cpArg, float* __restrict__ cpSum) {
    __shared__ unsigned char smem[36864];
    __shared__ float sRedM[256];
    __shared__ int   sRedA[256];
    __shared__ float sRedS[256];
    unsigned short* sAh = (unsigned short*)smem;          // [64][72]
    unsigned short* sAl = sAh + 64 * 72;
    unsigned short* sBh = sAl + 64 * 72;
    unsigned short* sBl = sBh + 64 * 72;
    float* S = (float*)smem;                               // [64][65] (epilogue alias)

    int tid = threadIdx.x;
    int m0 = blockIdx.y * 64, n0 = blockIdx.x * 64;
    int w = tid >> 6, l = tid & 63;
    int wm = w & 1, wn = w >> 1;
    int mr = l & 15, q = l >> 4;

    f32x4 acc[2][2];
#pragma unroll
    for (int a = 0; a < 2; ++a)
#pragma unroll
        for (int b = 0; b < 2; ++b)
#pragma unroll
            for (int u = 0; u < 4; ++u) acc[a][b][u] = 0.f;

    int r = tid >> 2;
    int k8 = (tid & 3) * 8;

    for (int k0 = 0; k0 < C_; k0 += 64) {
        size_t ga = (size_t)(m0 + r) * C_ + k0 + k8;
        size_t gb = (size_t)(n0 + r) * C_ + k0 + k8;
        uint4 a0 = *(const uint4*)(Ahi + ga);
        uint4 a1 = *(const uint4*)(Ahi + ga + 32);
        uint4 a2 = *(const uint4*)(Alo + ga);
        uint4 a3 = *(const uint4*)(Alo + ga + 32);
        uint4 b0 = *(const uint4*)(Bhi + gb);
        uint4 b1 = *(const uint4*)(Bhi + gb + 32);
        uint4 b2 = *(const uint4*)(Blo + gb);
        uint4 b3 = *(const uint4*)(Blo + gb + 32);
        *(uint4*)(sAh + r * 72 + k8)      = a0;
        *(uint4*)(sAh + r * 72 + k8 + 32) = a1;
        *(uint4*)(sAl + r * 72 + k8)      = a2;
        *(uint4*)(sAl + r * 72 + k8 + 32) = a3;
        *(uint4*)(sBh + r * 72 + k8)      = b0;
        *(uint4*)(sBh + r * 72 + k8 + 32) = b1;
        *(uint4*)(sBl + r * 72 + k8)      = b2;
        *(uint4*)(sBl + r * 72 + k8 + 32) = b3;
        __syncthreads();
#pragma unroll
        for (int ks = 0; ks < 64; ks += 32) {
            bf16x8 ah[2], al[2], bh[2], bl[2];
#pragma unroll
            for (int ti = 0; ti < 2; ++ti) {
                int mrow = wm * 32 + ti * 16 + mr;
                ah[ti] = *(const bf16x8*)(sAh + mrow * 72 + ks + q * 8);
                al[ti] = *(const bf16x8*)(sAl + mrow * 72 + ks + q * 8);
            }
#pragma unroll
            for (int tj = 0; tj < 2; ++tj) {
                int nrow = wn * 32 + tj * 16 + mr;
                bh[tj] = *(const bf16x8*)(sBh + nrow * 72 + ks + q * 8);
                bl[tj] = *(const bf16x8*)(sBl + nrow * 72 + ks + q * 8);
            }
#pragma unroll
            for (int ti = 0; ti < 2; ++ti)
#pragma unroll
                for (int tj = 0; tj < 2; ++tj) {
                    acc[ti][tj] = mfma16(ah[ti], bh[tj], acc[ti][tj]);
                    acc[ti][tj] = mfma16(ah[ti], bl[tj], acc[ti][tj]);
                    acc[ti][tj] = mfma16(al[ti], bh[tj], acc[ti][tj]);
                }
        }
        __syncthreads();
    }

    // ---- epilogue: dump S tile to LDS (fp32) ----
#pragma unroll
    for (int ti = 0; ti < 2; ++ti)
#pragma unroll
        for (int tj = 0; tj < 2; ++tj)
#pragma unroll
            for (int rg = 0; rg < 4; ++rg)
                S[(wm * 32 + ti * 16 + q * 4 + rg) * 65 + wn * 32 + tj * 16 + mr] = acc[ti][tj][rg];
    __syncthreads();

    // row stats: 4 threads per row, 16 cols each (ascending -> first-occurrence argmax)
    {
        int rr = tid >> 2, q4 = tid & 3;
        float mx = -1e30f; int ag = 0; float sm = 0.f;
        for (int cc = 0; cc < 16; ++cc) {
            int c = q4 * 16 + cc;
            float v = S[rr * 65 + c];
            sm += __expf(v);
            if (v > mx) { mx = v; ag = c; }
        }
        sRedM[tid] = mx; sRedA[tid] = ag; sRedS[tid] = sm;
    }
    __syncthreads();
    if (tid < 64) {
        float mx = -1e30f; int ag = 0; float sm = 0.f;
        for (int qq = 0; qq < 4; ++qq) {
            float v = sRedM[tid * 4 + qq];
            if (v > mx) { mx = v; ag = sRedA[tid * 4 + qq]; }
            sm += sRedS[tid * 4 + qq];
        }
        size_t o = (size_t)blockIdx.x * N_ + m0 + tid;
        rpMax[o] = mx; rpArg[o] = n0 + ag; rpSum[o] = sm;
    }
    __syncthreads();
    // col stats
    {
        int cc = tid >> 2, q4 = tid & 3;
        float mx = -1e30f; int ag = 0; float sm = 0.f;
        for (int rr = 0; rr < 16; ++rr) {
            int rrr = q4 * 16 + rr;
            float v = S[rrr * 65 + cc];
            sm += __expf(v);
            if (v > mx) { mx = v; ag = rrr; }
        }
        sRedM[tid] = mx; sRedA[tid] = ag; sRedS[tid] = sm;
    }
    __syncthreads();
    if (tid < 64) {
        float mx = -1e30f; int ag = 0; float sm = 0.f;
        for (int qq = 0; qq < 4; ++qq) {
            float v = sRedM[tid * 4 + qq];
            if (v > mx) { mx = v; ag = sRedA[tid * 4 + qq]; }
            sm += sRedS[tid * 4 + qq];
        }
        size_t o = (size_t)blockIdx.y * N_ + n0 + tid;
        cpMax[o] = mx; cpArg[o] = m0 + ag; cpSum[o] = sm;
    }
    // E store (bf16 of exp(S)), row-major
    {
        int r2 = tid >> 2, cq = (tid & 3) * 16;
        unsigned short tmp[16] __attribute__((aligned(16)));
        for (int u = 0; u < 16; ++u) tmp[u] = f2bf(__expf(S[r2 * 65 + cq + u]));
        unsigned short* dst = E + (size_t)(m0 + r2) * N_ + n0 + cq;
        *(uint4*)dst = *(const uint4*)tmp;
        *(uint4*)(dst + 8) = *(const uint4*)(tmp + 8);
    }
    // ET store (bf16 of exp(S^T)), row-major in n
    {
        int n2 = tid >> 2, mq = (tid & 3) * 16;
        unsigned short tmp[16] __attribute__((aligned(16)));
        for (int u = 0; u < 16; ++u) tmp[u] = f2bf(__expf(S[(mq + u) * 65 + n2]));
        unsigned short* dst = ET + (size_t)(n0 + n2) * N_ + m0 + mq;
        *(uint4*)dst = *(const uint4*)tmp;
        *(uint4*)(dst + 8) = *(const uint4*)(tmp + 8);
    }
}

// ---- fused merge of row/col tile-partials (dir = blockIdx.y) ----
__global__ void merge_k(const float* __restrict__ rpMax, const int* __restrict__ rpArg,
                        const float* __restrict__ rpSum, const float* __restrict__ cpMax,
                        const int* __restrict__ cpArg, const float* __restrict__ cpSum,
                        int* __restrict__ rowArg, float* __restrict__ rowSum,
                        int* __restrict__ colArg, float* __restrict__ colSum) {
    int d = blockIdx.y;
    const float* pMax = d ? cpMax : rpMax;
    const int*   pArg = d ? cpArg : rpArg;
    const float* pSum = d ? cpSum : rpSum;
    int*   outArg = d ? colArg : rowArg;
    float* outSum = d ? colSum : rowSum;
    int m = blockIdx.x * 256 + threadIdx.x;
    float mx = -1e30f; int ag = 0; float sm = 0.f;
    for (int t = 0; t < 64; ++t) {
        float v = pMax[(size_t)t * N_ + m];
        if (v > mx) { mx = v; ag = pArg[(size_t)t * N_ + m]; }
        sm += pSum[(size_t)t * N_ + m];
    }
    outArg[m] = ag; outSum[m] = sm;
}

// ---- pass2: both dirs + split-K in one launch; plain stores to slices ----
// grid: (4 c-tiles, 64 m-tiles, 4 = dir*2+ks)
__global__ __launch_bounds__(256) void p2_k(
    const unsigned short* __restrict__ E, const unsigned short* __restrict__ ET,
    const unsigned short* __restrict__ sfT, int iview, int jview,
    float* __restrict__ accb) {
    __shared__ unsigned short sA[64 * 72];
    __shared__ unsigned short sB[64 * 72];
    int tid = threadIdx.x;
    int d = blockIdx.z >> 1, ks = blockIdx.z & 1;
    const unsigned short* A = d ? ET : E;
    const unsigned short* B = sfT + (size_t)(d ? iview : jview) * C_ * N_;
    int c0 = blockIdx.x * 64, m0 = blockIdx.y * 64;
    int kbase = ks * 2048;
    int w = tid >> 6, l = tid & 63, wm = w & 1, wn = w >> 1;
    int mr = l & 15, q = l >> 4;
    f32x4 acc[2][2];
#pragma unroll
    for (int a = 0; a < 2; ++a)
#pragma unroll
        for (int b = 0; b < 2; ++b)
#pragma unroll
            for (int u = 0; u < 4; ++u) acc[a][b][u] = 0.f;
    int r = tid >> 2, k8 = (tid & 3) * 8;
    for (int k0 = kbase; k0 < kbase + 2048; k0 += 64) {
        uint4 a0 = *(const uint4*)(A + (size_t)(m0 + r) * N_ + k0 + k8);
        uint4 a1 = *(const uint4*)(A + (size_t)(m0 + r) * N_ + k0 + k8 + 32);
        uint4 b0 = *(const uint4*)(B + (size_t)(c0 + r) * N_ + k0 + k8);
        uint4 b1 = *(const uint4*)(B + (size_t)(c0 + r) * N_ + k0 + k8 + 32);
        *(uint4*)(sA + r * 72 + k8)      = a0;
        *(uint4*)(sA + r * 72 + k8 + 32) = a1;
        *(uint4*)(sB + r * 72 + k8)      = b0;
        *(uint4*)(sB + r * 72 + k8 + 32) = b1;
        __syncthreads();
#pragma unroll
        for (int ksub = 0; ksub < 64; ksub += 32) {
            bf16x8 af[2], bfr[2];
#pragma unroll
            for (int ti = 0; ti < 2; ++ti)
                af[ti] = *(const bf16x8*)(sA + (wm * 32 + ti * 16 + mr) * 72 + ksub + q * 8);
#pragma unroll
            for (int tj = 0; tj < 2; ++tj)
                bfr[tj] = *(const bf16x8*)(sB + (wn * 32 + tj * 16 + mr) * 72 + ksub + q * 8);
#pragma unroll
            for (int ti = 0; ti < 2; ++ti)
#pragma unroll
                for (int tj = 0; tj < 2; ++tj)
                    acc[ti][tj] = mfma16(af[ti], bfr[tj], acc[ti][tj]);
        }
        __syncthreads();
    }
    float* accs = accb + (size_t)blockIdx.z * N_ * C_;
#pragma unroll
    for (int ti = 0; ti < 2; ++ti)
#pragma unroll
        for (int tj = 0; tj < 2; ++tj) {
            int c = c0 + wn * 32 + tj * 16 + mr;
#pragma unroll
            for (int rg = 0; rg < 4; ++rg) {
                int m = m0 + wm * 32 + ti * 16 + q * 4 + rg;
                accs[(size_t)m * C_ + c] = acc[ti][tj][rg];
            }
        }
}

// ---- loss: combine slices, mask (computed inline), reduce ----
__global__ __launch_bounds__(256) void loss_k(
    const float* __restrict__ accb, const int* __restrict__ rowArg,
    const int* __restrict__ colArg, const float* __restrict__ rowSum,
    const float* __restrict__ colSum, const float* __restrict__ Ri,
    const float* __restrict__ Rj, const float* __restrict__ relwt,
    int pid0, int pid1, float* __restrict__ pairSq, int* __restrict__ pairCnt) {
    int d = blockIdx.y;
    int r0 = blockIdx.x * 256;
    const float* s0 = accb + (size_t)(d * 2) * N_ * C_;
    const float* s1 = s0 + (size_t)N_ * C_;
    const int* fa = d ? colArg : rowArg;
    const int* ba = d ? rowArg : colArg;
    const float* sum = d ? colSum : rowSum;
    const float* Rr = d ? Rj : Ri;
    int pid = d ? pid1 : pid0;
    const float* rw = relwt + (size_t)pid * C_;
    int c = threadIdx.x;
    float rwc = rw[c];
    float local = 0.f; int cntLocal = 0;
    for (int rr = 0; rr < 256; ++rr) {
        int y = r0 + rr;
        int mut = (ba[fa[y]] == y) ? 1 : 0;
        if (mut) {
            ++cntLocal;
            float soft = (s0[(size_t)y * C_ + c] + s1[(size_t)y * C_ + c]) / sum[y];
            float dv = Rr[(size_t)y * C_ + c] + rwc - soft;
            local += dv * dv;
        }
    }
    __shared__ float red[256];
    red[c] = local;
    __syncthreads();
    for (int s = 128; s > 0; s >>= 1) {
        if (c < s) red[c] += red[c + s];
        __syncthreads();
    }
    if (c == 0) {
        atomicAdd(pairSq + pid, red[0]);
        atomicAdd(pairCnt + pid, cntLocal);
    }
}

// ---- final scalar combine ----
__global__ void final_k(const float* __restrict__ sq, const int* __restrict__ cnt,
                        float* __restrict__ out) {
    if (threadIdx.x == 0 && blockIdx.x == 0) {
        float loss = 0.f, count = 0.f;
        for (int p = 0; p < 16; ++p) {
            int i = p >> 2, j = p & 3;
            if (i == j) continue;
            float ns = (float)cnt[p];
            if (ns > 0.f) { loss += sq[p] / fmaxf(ns * (float)C_, 1.0f); count += 1.f; }
        }
        out[0] = (count > 0.f) ? loss / count : 0.f;
    }
}

extern "C" void kernel_launch(void* const* d_in, const int* in_sizes, int n_in,
                              void* d_out, int out_size, void* d_ws, size_t ws_size,
                              hipStream_t stream) {
    const float* desc = (const float*)d_in[0];
    const float* sf   = (const float*)d_in[1];
    const float* T    = (const float*)d_in[2];
    const float* Wrec = (const float*)d_in[3];
    const float* WT   = (const float*)d_in[4];
    float* out = (float*)d_out;
    char* ws = (char*)d_ws;

    float*          dn    = (float*)(ws + OFF_DN);
    float*          R     = (float*)(ws + OFF_R);
    unsigned short* dnh   = (unsigned short*)(ws + OFF_DNHI);
    unsigned short* dnl   = (unsigned short*)(ws + OFF_DNLO);
    unsigned short* sfT   = (unsigned short*)(ws + OFF_SFT);
    unsigned short* E     = (unsigned short*)(ws + OFF_E);
    unsigned short* ET    = (unsigned short*)(ws + OFF_ET);
    float* accb  = (float*)(ws + OFF_ACC);
    float* rpMax = (float*)(ws + OFF_RPMAX);
    int*   rpArg = (int*)(ws + OFF_RPARG);
    float* rpSum = (float*)(ws + OFF_RPSUM);
    float* cpMax = (float*)(ws + OFF_CPMAX);
    int*   cpArg = (int*)(ws + OFF_CPARG);
    float* cpSum = (float*)(ws + OFF_CPSUM);
    int*   rowArg = (int*)(ws + OFF_RARG);
    float* rowSum = (float*)(ws + OFF_RSUM);
    int*   colArg = (int*)(ws + OFF_CARG);
    float* colSum = (float*)(ws + OFF_CSUM);
    float* relwt = (float*)(ws + OFF_RELWT);
    float* pairSq = (float*)(ws + OFF_SQ);
    int*   pairCnt = (int*)(ws + OFF_CNT);

    normalize_k<<<N_ * V_, 256, 0, stream>>>(desc, dn, dnh, dnl);
    rmatmul_k<<<dim3(N_ / 16, V_), 256, 0, stream>>>(dn, Wrec, R);
    sfT_k<<<dim3(64, 4, 4), 256, 0, stream>>>(sf, sfT);
    relwt_k<<<16, 256, 0, stream>>>(T, WT, relwt);
    zero_k<<<1, 64, 0, stream>>>(pairSq, pairCnt);

    for (int i = 0; i < V_; ++i) {
        for (int j = i + 1; j < V_; ++j) {
            const unsigned short* Ahi = dnh + (size_t)i * N_ * C_;
            const unsigned short* Alo = dnl + (size_t)i * N_ * C_;
            const unsigned short* Bhi = dnh + (size_t)j * N_ * C_;
            const unsigned short* Blo = dnl + (size_t)j * N_ * C_;
            sim_mfma_k<<<dim3(64, 64), 256, 0, stream>>>(
                Ahi, Alo, Bhi, Blo, E, ET, rpMax, rpArg, rpSum, cpMax, cpArg, cpSum);
            merge_k<<<dim3(16, 2), 256, 0, stream>>>(
                rpMax, rpArg, rpSum, cpMax, cpArg, cpSum, rowArg, rowSum, colArg, colSum);
            int pid0 = i * 4 + j, pid1 = j * 4 + i;
            p2_k<<<dim3(4, 64, 4), 256, 0, stream>>>(E, ET, sfT, i, j, accb);
            loss_k<<<dim3(16, 2), 256, 0, stream>>>(
                accb, rowArg, colArg, rowSum, colSum,
                R + (size_t)i * N_ * C_, R + (size_t)j * N_ * C_,
                relwt, pid0, pid1, pairSq, pairCnt);
        }
    }
    final_k<<<1, 64, 0, stream>>>(pairSq, pairCnt, out);
}

// Round 4
// 788.581 us; speedup vs baseline: 5.9822x; 1.7478x over previous
//
#include <hip/hip_runtime.h>
#include <math.h>

#define N_ 4096
#define V_ 4
#define C_ 256

typedef __attribute__((ext_vector_type(8))) short bf16x8;
typedef __attribute__((ext_vector_type(4))) float f32x4;

// ---------------- workspace byte offsets ----------------
#define OFF_DN     0ull
#define OFF_R      16777216ull
#define OFF_DNHI   33554432ull
#define OFF_DNLO   41943040ull
#define OFF_SFT    50331648ull
#define OFF_E      58720256ull
#define OFF_ET     92274688ull
#define OFF_RPMAX  125829120ull
#define OFF_RPARG  126877696ull
#define OFF_RPSUM  127926272ull
#define OFF_CPMAX  128974848ull
#define OFF_CPARG  130023424ull
#define OFF_CPSUM  131072000ull
#define OFF_RARG   132120576ull
#define OFF_RSUM   132136960ull
#define OFF_CARG   132153344ull
#define OFF_CSUM   132169728ull
#define OFF_RELWT  132186112ull
#define OFF_SQ     132202496ull
#define OFF_CNT    132202560ull

__device__ __forceinline__ unsigned short f2bf(float x) {
    unsigned int u = __float_as_uint(x);
    u += 0x7fffu + ((u >> 16) & 1u);
    return (unsigned short)(u >> 16);
}
__device__ __forceinline__ float bf2f(unsigned short h) {
    return __uint_as_float(((unsigned int)h) << 16);
}
__device__ __forceinline__ f32x4 mfma16(bf16x8 a, bf16x8 b, f32x4 c) {
    return __builtin_amdgcn_mfma_f32_16x16x32_bf16(a, b, c, 0, 0, 0);
}

// ---- normalize + bf16 hi/lo split: dn[v][n][c] ----
__global__ void normalize_k(const float* __restrict__ desc, float* __restrict__ dn,
                            unsigned short* __restrict__ dnh, unsigned short* __restrict__ dnl) {
    int row = blockIdx.x;            // n*V + v
    int n = row >> 2, v = row & 3;
    int c = threadIdx.x;
    float x = desc[(size_t)row * C_ + c];
    __shared__ float red[256];
    red[c] = x * x;
    __syncthreads();
    for (int s = 128; s > 0; s >>= 1) {
        if (c < s) red[c] += red[c + s];
        __syncthreads();
    }
    float inv = 1.0f / fmaxf(sqrtf(red[0]), 1e-12f);
    float y = x * inv;
    size_t o = ((size_t)v * N_ + n) * C_ + c;
    dn[o] = y;
    unsigned short h = f2bf(y);
    dnh[o] = h;
    dnl[o] = f2bf(y - bf2f(h));
}

// ---- R_v = dn_v @ W_rec ----
__global__ void rmatmul_k(const float* __restrict__ dn, const float* __restrict__ Wrec,
                          float* __restrict__ R) {
    int v = blockIdx.y;
    int m0 = blockIdx.x * 16;
    __shared__ float rows[16][C_];
    const float* base = dn + ((size_t)v * N_ + m0) * C_;
    for (int r = 0; r < 16; ++r) rows[r][threadIdx.x] = base[(size_t)r * C_ + threadIdx.x];
    __syncthreads();
    float acc[16];
#pragma unroll
    for (int r = 0; r < 16; ++r) acc[r] = 0.f;
    int c = threadIdx.x;
    for (int k = 0; k < C_; ++k) {
        float w = Wrec[(size_t)k * C_ + c];
#pragma unroll
        for (int r = 0; r < 16; ++r) acc[r] += rows[r][k] * w;
    }
    float* outp = R + ((size_t)v * N_ + m0) * C_ + c;
    for (int r = 0; r < 16; ++r) outp[(size_t)r * C_] = acc[r];
}

// ---- relWT[p][c], p = i*4+j ----
__global__ void relwt_k(const float* __restrict__ T, const float* __restrict__ WT,
                        float* __restrict__ relwt) {
    int p = blockIdx.x; int i = p >> 2, j = p & 3;
    if (i == j) return;
    int c = threadIdx.x;
    float acc = 0.f;
    for (int k = 0; k < 16; ++k) acc += T[i * 16 + k] * WT[(size_t)k * C_ + c];
    for (int k = 0; k < 16; ++k) acc += T[j * 16 + k] * WT[(size_t)(16 + k) * C_ + c];
    relwt[(size_t)p * C_ + c] = acc;
}

// ---- sfT[v][c][n] = bf16(sf[n][v][c]) ----
__global__ void sfT_k(const float* __restrict__ sf, unsigned short* __restrict__ sfT) {
    __shared__ unsigned short Tt[64 * 72];   // [c][n], pitch 72
    int n0 = blockIdx.x * 64, c0 = blockIdx.y * 64, v = blockIdx.z;
    int t = threadIdx.x;
    int nr = t >> 2, cq = (t & 3) * 16;
    const float* src = sf + ((size_t)(n0 + nr) * V_ + v) * C_ + c0 + cq;
    for (int u = 0; u < 16; ++u) Tt[(cq + u) * 72 + nr] = f2bf(src[u]);
    __syncthreads();
    int cr = t >> 2, nq = (t & 3) * 16;
    unsigned short tmp[16] __attribute__((aligned(16)));
    for (int u = 0; u < 16; ++u) tmp[u] = Tt[cr * 72 + nq + u];
    unsigned short* dst = sfT + ((size_t)v * C_ + c0 + cr) * N_ + n0 + nq;
    *(uint4*)dst = *(const uint4*)tmp;
    *(uint4*)(dst + 8) = *(const uint4*)(tmp + 8);
}

__global__ void zero_k(float* sq, int* cnt) {
    if (threadIdx.x < 16) { sq[threadIdx.x] = 0.f; cnt[threadIdx.x] = 0; }
}

// ---- sim GEMM (split-bf16, 3 MFMA) + fused stats/E/ET epilogue ----
__global__ __launch_bounds__(256) void sim_mfma_k(
    const unsigned short* __restrict__ Ahi, const unsigned short* __restrict__ Alo,
    const unsigned short* __restrict__ Bhi, const unsigned short* __restrict__ Blo,
    unsigned short* __restrict__ E, unsigned short* __restrict__ ET,
    float* __restrict__ rpMax, int* __restrict__ rpArg, float* __restrict__ rpSum,
    float* __restrict__ cpMax, int* __restrict__ cpArg, float* __restrict__ cpSum) {
    __shared__ unsigned char smem[36864];
    __shared__ float sRedM[256];
    __shared__ int   sRedA[256];
    __shared__ float sRedS[256];
    unsigned short* sAh = (unsigned short*)smem;          // [64][72]
    unsigned short* sAl = sAh + 64 * 72;
    unsigned short* sBh = sAl + 64 * 72;
    unsigned short* sBl = sBh + 64 * 72;
    float* S = (float*)smem;                               // [64][65] (epilogue alias)

    int tid = threadIdx.x;
    int m0 = blockIdx.y * 64, n0 = blockIdx.x * 64;
    int w = tid >> 6, l = tid & 63;
    int wm = w & 1, wn = w >> 1;
    int mr = l & 15, q = l >> 4;

    f32x4 acc[2][2];
#pragma unroll
    for (int a = 0; a < 2; ++a)
#pragma unroll
        for (int b = 0; b < 2; ++b)
#pragma unroll
            for (int u = 0; u < 4; ++u) acc[a][b][u] = 0.f;

    int r = tid >> 2;
    int k8 = (tid & 3) * 8;

    for (int k0 = 0; k0 < C_; k0 += 64) {
        size_t ga = (size_t)(m0 + r) * C_ + k0 + k8;
        size_t gb = (size_t)(n0 + r) * C_ + k0 + k8;
        uint4 a0 = *(const uint4*)(Ahi + ga);
        uint4 a1 = *(const uint4*)(Ahi + ga + 32);
        uint4 a2 = *(const uint4*)(Alo + ga);
        uint4 a3 = *(const uint4*)(Alo + ga + 32);
        uint4 b0 = *(const uint4*)(Bhi + gb);
        uint4 b1 = *(const uint4*)(Bhi + gb + 32);
        uint4 b2 = *(const uint4*)(Blo + gb);
        uint4 b3 = *(const uint4*)(Blo + gb + 32);
        *(uint4*)(sAh + r * 72 + k8)      = a0;
        *(uint4*)(sAh + r * 72 + k8 + 32) = a1;
        *(uint4*)(sAl + r * 72 + k8)      = a2;
        *(uint4*)(sAl + r * 72 + k8 + 32) = a3;
        *(uint4*)(sBh + r * 72 + k8)      = b0;
        *(uint4*)(sBh + r * 72 + k8 + 32) = b1;
        *(uint4*)(sBl + r * 72 + k8)      = b2;
        *(uint4*)(sBl + r * 72 + k8 + 32) = b3;
        __syncthreads();
#pragma unroll
        for (int ks = 0; ks < 64; ks += 32) {
            bf16x8 ah[2], al[2], bh[2], bl[2];
#pragma unroll
            for (int ti = 0; ti < 2; ++ti) {
                int mrow = wm * 32 + ti * 16 + mr;
                ah[ti] = *(const bf16x8*)(sAh + mrow * 72 + ks + q * 8);
                al[ti] = *(const bf16x8*)(sAl + mrow * 72 + ks + q * 8);
            }
#pragma unroll
            for (int tj = 0; tj < 2; ++tj) {
                int nrow = wn * 32 + tj * 16 + mr;
                bh[tj] = *(const bf16x8*)(sBh + nrow * 72 + ks + q * 8);
                bl[tj] = *(const bf16x8*)(sBl + nrow * 72 + ks + q * 8);
            }
#pragma unroll
            for (int ti = 0; ti < 2; ++ti)
#pragma unroll
                for (int tj = 0; tj < 2; ++tj) {
                    acc[ti][tj] = mfma16(ah[ti], bh[tj], acc[ti][tj]);
                    acc[ti][tj] = mfma16(ah[ti], bl[tj], acc[ti][tj]);
                    acc[ti][tj] = mfma16(al[ti], bh[tj], acc[ti][tj]);
                }
        }
        __syncthreads();
    }

    // ---- epilogue: dump S tile to LDS (fp32) ----
#pragma unroll
    for (int ti = 0; ti < 2; ++ti)
#pragma unroll
        for (int tj = 0; tj < 2; ++tj)
#pragma unroll
            for (int rg = 0; rg < 4; ++rg)
                S[(wm * 32 + ti * 16 + q * 4 + rg) * 65 + wn * 32 + tj * 16 + mr] = acc[ti][tj][rg];
    __syncthreads();

    // row stats: 4 threads per row, 16 cols each (ascending -> first-occurrence argmax)
    {
        int rr = tid >> 2, q4 = tid & 3;
        float mx = -1e30f; int ag = 0; float sm = 0.f;
        for (int cc = 0; cc < 16; ++cc) {
            int c = q4 * 16 + cc;
            float v = S[rr * 65 + c];
            sm += __expf(v);
            if (v > mx) { mx = v; ag = c; }
        }
        sRedM[tid] = mx; sRedA[tid] = ag; sRedS[tid] = sm;
    }
    __syncthreads();
    if (tid < 64) {
        float mx = -1e30f; int ag = 0; float sm = 0.f;
        for (int qq = 0; qq < 4; ++qq) {
            float v = sRedM[tid * 4 + qq];
            if (v > mx) { mx = v; ag = sRedA[tid * 4 + qq]; }
            sm += sRedS[tid * 4 + qq];
        }
        size_t o = (size_t)blockIdx.x * N_ + m0 + tid;
        rpMax[o] = mx; rpArg[o] = n0 + ag; rpSum[o] = sm;
    }
    __syncthreads();
    // col stats
    {
        int cc = tid >> 2, q4 = tid & 3;
        float mx = -1e30f; int ag = 0; float sm = 0.f;
        for (int rr = 0; rr < 16; ++rr) {
            int rrr = q4 * 16 + rr;
            float v = S[rrr * 65 + cc];
            sm += __expf(v);
            if (v > mx) { mx = v; ag = rrr; }
        }
        sRedM[tid] = mx; sRedA[tid] = ag; sRedS[tid] = sm;
    }
    __syncthreads();
    if (tid < 64) {
        float mx = -1e30f; int ag = 0; float sm = 0.f;
        for (int qq = 0; qq < 4; ++qq) {
            float v = sRedM[tid * 4 + qq];
            if (v > mx) { mx = v; ag = sRedA[tid * 4 + qq]; }
            sm += sRedS[tid * 4 + qq];
        }
        size_t o = (size_t)blockIdx.y * N_ + n0 + tid;
        cpMax[o] = mx; cpArg[o] = m0 + ag; cpSum[o] = sm;
    }
    // E store (bf16 of exp(S)), row-major
    {
        int r2 = tid >> 2, cq = (tid & 3) * 16;
        unsigned short tmp[16] __attribute__((aligned(16)));
        for (int u = 0; u < 16; ++u) tmp[u] = f2bf(__expf(S[r2 * 65 + cq + u]));
        unsigned short* dst = E + (size_t)(m0 + r2) * N_ + n0 + cq;
        *(uint4*)dst = *(const uint4*)tmp;
        *(uint4*)(dst + 8) = *(const uint4*)(tmp + 8);
    }
    // ET store (bf16 of exp(S^T)), row-major in n
    {
        int n2 = tid >> 2, mq = (tid & 3) * 16;
        unsigned short tmp[16] __attribute__((aligned(16)));
        for (int u = 0; u < 16; ++u) tmp[u] = f2bf(__expf(S[(mq + u) * 65 + n2]));
        unsigned short* dst = ET + (size_t)(n0 + n2) * N_ + m0 + mq;
        *(uint4*)dst = *(const uint4*)tmp;
        *(uint4*)(dst + 8) = *(const uint4*)(tmp + 8);
    }
}

// ---- fused merge of row/col tile-partials; grid (64, 2), 4 t-groups/block ----
__global__ __launch_bounds__(256) void merge_k(
    const float* __restrict__ rpMax, const int* __restrict__ rpArg,
    const float* __restrict__ rpSum, const float* __restrict__ cpMax,
    const int* __restrict__ cpArg, const float* __restrict__ cpSum,
    int* __restrict__ rowArg, float* __restrict__ rowSum,
    int* __restrict__ colArg, float* __restrict__ colSum) {
    int d = blockIdx.y;
    const float* pMax = d ? cpMax : rpMax;
    const int*   pArg = d ? cpArg : rpArg;
    const float* pSum = d ? cpSum : rpSum;
    int*   outArg = d ? colArg : rowArg;
    float* outSum = d ? colSum : rowSum;
    int tid = threadIdx.x;
    int li = tid & 63, g = tid >> 6;
    int m = blockIdx.x * 64 + li;
    float mx = -1e30f; int ag = 0; float sm = 0.f;
    for (int t = g * 16; t < g * 16 + 16; ++t) {
        float v = pMax[(size_t)t * N_ + m];
        if (v > mx) { mx = v; ag = pArg[(size_t)t * N_ + m]; }
        sm += pSum[(size_t)t * N_ + m];
    }
    __shared__ float sMx[256], sSm[256];
    __shared__ int sAg[256];
    sMx[g * 64 + li] = mx; sAg[g * 64 + li] = ag; sSm[g * 64 + li] = sm;
    __syncthreads();
    if (tid < 64) {
        float M = sMx[tid]; int A = sAg[tid]; float Ssum = sSm[tid];
        for (int gg = 1; gg < 4; ++gg) {
            float v = sMx[gg * 64 + tid];
            if (v > M) { M = v; A = sAg[gg * 64 + tid]; }
            Ssum += sSm[gg * 64 + tid];
        }
        outArg[m] = A; outSum[m] = Ssum;
    }
}

// ---- pass2: both dirs in one launch, fused loss epilogue ----
// grid: (4 c-tiles, 64 m-tiles, 2 dirs)
__global__ __launch_bounds__(256) void p2_k(
    const unsigned short* __restrict__ E, const unsigned short* __restrict__ ET,
    const unsigned short* __restrict__ sfT, int iview, int jview,
    const int* __restrict__ rowArg, const int* __restrict__ colArg,
    const float* __restrict__ rowSum, const float* __restrict__ colSum,
    const float* __restrict__ Ri, const float* __restrict__ Rj,
    const float* __restrict__ relwt, int pid0, int pid1,
    float* __restrict__ pairSq, int* __restrict__ pairCnt) {
    __shared__ unsigned short sA[64 * 72];
    __shared__ unsigned short sB[64 * 72];
    __shared__ float red[256];
    __shared__ int   mutS[64];
    __shared__ float invS[64];
    int tid = threadIdx.x;
    int d = blockIdx.z;
    const unsigned short* A = d ? ET : E;
    const unsigned short* B = sfT + (size_t)(d ? iview : jview) * C_ * N_;
    const int* fa = d ? colArg : rowArg;
    const int* ba = d ? rowArg : colArg;
    const float* sumE = d ? colSum : rowSum;
    const float* Rr = d ? Rj : Ri;
    int pid = d ? pid1 : pid0;
    int c0 = blockIdx.x * 64, m0 = blockIdx.y * 64;
    int w = tid >> 6, l = tid & 63, wm = w & 1, wn = w >> 1;
    int mr = l & 15, q = l >> 4;
    if (tid < 64) {
        int y = m0 + tid;
        mutS[tid] = (ba[fa[y]] == y) ? 1 : 0;
        invS[tid] = 1.0f / sumE[y];
    }
    f32x4 acc[2][2];
#pragma unroll
    for (int a = 0; a < 2; ++a)
#pragma unroll
        for (int b = 0; b < 2; ++b)
#pragma unroll
            for (int u = 0; u < 4; ++u) acc[a][b][u] = 0.f;
    int r = tid >> 2, k8 = (tid & 3) * 8;
    for (int k0 = 0; k0 < N_; k0 += 64) {
        uint4 a0 = *(const uint4*)(A + (size_t)(m0 + r) * N_ + k0 + k8);
        uint4 a1 = *(const uint4*)(A + (size_t)(m0 + r) * N_ + k0 + k8 + 32);
        uint4 b0 = *(const uint4*)(B + (size_t)(c0 + r) * N_ + k0 + k8);
        uint4 b1 = *(const uint4*)(B + (size_t)(c0 + r) * N_ + k0 + k8 + 32);
        *(uint4*)(sA + r * 72 + k8)      = a0;
        *(uint4*)(sA + r * 72 + k8 + 32) = a1;
        *(uint4*)(sB + r * 72 + k8)      = b0;
        *(uint4*)(sB + r * 72 + k8 + 32) = b1;
        __syncthreads();
#pragma unroll
        for (int ksub = 0; ksub < 64; ksub += 32) {
            bf16x8 af[2], bfr[2];
#pragma unroll
            for (int ti = 0; ti < 2; ++ti)
                af[ti] = *(const bf16x8*)(sA + (wm * 32 + ti * 16 + mr) * 72 + ksub + q * 8);
#pragma unroll
            for (int tj = 0; tj < 2; ++tj)
                bfr[tj] = *(const bf16x8*)(sB + (wn * 32 + tj * 16 + mr) * 72 + ksub + q * 8);
#pragma unroll
            for (int ti = 0; ti < 2; ++ti)
#pragma unroll
                for (int tj = 0; tj < 2; ++tj)
                    acc[ti][tj] = mfma16(af[ti], bfr[tj], acc[ti][tj]);
        }
        __syncthreads();
    }
    const float* rw = relwt + (size_t)pid * C_;
    float local = 0.f;
#pragma unroll
    for (int ti = 0; ti < 2; ++ti)
#pragma unroll
        for (int tj = 0; tj < 2; ++tj) {
            int c = c0 + wn * 32 + tj * 16 + mr;
            float rwc = rw[c];
#pragma unroll
            for (int rg = 0; rg < 4; ++rg) {
                int ml = wm * 32 + ti * 16 + q * 4 + rg;
                if (mutS[ml]) {
                    int m = m0 + ml;
                    float soft = acc[ti][tj][rg] * invS[ml];
                    float dv = Rr[(size_t)m * C_ + c] + rwc - soft;
                    local += dv * dv;
                }
            }
        }
    red[tid] = local;
    __syncthreads();
    for (int s = 128; s > 0; s >>= 1) {
        if (tid < s) red[tid] += red[tid + s];
        __syncthreads();
    }
    if (tid == 0) atomicAdd(pairSq + pid, red[0]);
    // mutual count: one c-tile per m-tile contributes
    if (blockIdx.x == 0) {
        __syncthreads();
        if (tid == 0) {
            int cnt = 0;
            for (int u = 0; u < 64; ++u) cnt += mutS[u];
            atomicAdd(pairCnt + pid, cnt);
        }
    }
}

// ---- final scalar combine ----
__global__ void final_k(const float* __restrict__ sq, const int* __restrict__ cnt,
                        float* __restrict__ out) {
    if (threadIdx.x == 0 && blockIdx.x == 0) {
        float loss = 0.f, count = 0.f;
        for (int p = 0; p < 16; ++p) {
            int i = p >> 2, j = p & 3;
            if (i == j) continue;
            float ns = (float)cnt[p];
            if (ns > 0.f) { loss += sq[p] / fmaxf(ns * (float)C_, 1.0f); count += 1.f; }
        }
        out[0] = (count > 0.f) ? loss / count : 0.f;
    }
}

extern "C" void kernel_launch(void* const* d_in, const int* in_sizes, int n_in,
                              void* d_out, int out_size, void* d_ws, size_t ws_size,
                              hipStream_t stream) {
    const float* desc = (const float*)d_in[0];
    const float* sf   = (const float*)d_in[1];
    const float* T    = (const float*)d_in[2];
    const float* Wrec = (const float*)d_in[3];
    const float* WT   = (const float*)d_in[4];
    float* out = (float*)d_out;
    char* ws = (char*)d_ws;

    float*          dn    = (float*)(ws + OFF_DN);
    float*          R     = (float*)(ws + OFF_R);
    unsigned short* dnh   = (unsigned short*)(ws + OFF_DNHI);
    unsigned short* dnl   = (unsigned short*)(ws + OFF_DNLO);
    unsigned short* sfT   = (unsigned short*)(ws + OFF_SFT);
    unsigned short* E     = (unsigned short*)(ws + OFF_E);
    unsigned short* ET    = (unsigned short*)(ws + OFF_ET);
    float* rpMax = (float*)(ws + OFF_RPMAX);
    int*   rpArg = (int*)(ws + OFF_RPARG);
    float* rpSum = (float*)(ws + OFF_RPSUM);
    float* cpMax = (float*)(ws + OFF_CPMAX);
    int*   cpArg = (int*)(ws + OFF_CPARG);
    float* cpSum = (float*)(ws + OFF_CPSUM);
    int*   rowArg = (int*)(ws + OFF_RARG);
    float* rowSum = (float*)(ws + OFF_RSUM);
    int*   colArg = (int*)(ws + OFF_CARG);
    float* colSum = (float*)(ws + OFF_CSUM);
    float* relwt = (float*)(ws + OFF_RELWT);
    float* pairSq = (float*)(ws + OFF_SQ);
    int*   pairCnt = (int*)(ws + OFF_CNT);

    normalize_k<<<N_ * V_, 256, 0, stream>>>(desc, dn, dnh, dnl);
    rmatmul_k<<<dim3(N_ / 16, V_), 256, 0, stream>>>(dn, Wrec, R);
    sfT_k<<<dim3(64, 4, 4), 256, 0, stream>>>(sf, sfT);
    relwt_k<<<16, 256, 0, stream>>>(T, WT, relwt);
    zero_k<<<1, 64, 0, stream>>>(pairSq, pairCnt);

    for (int i = 0; i < V_; ++i) {
        for (int j = i + 1; j < V_; ++j) {
            const unsigned short* Ahi = dnh + (size_t)i * N_ * C_;
            const unsigned short* Alo = dnl + (size_t)i * N_ * C_;
            const unsigned short* Bhi = dnh + (size_t)j * N_ * C_;
            const unsigned short* Blo = dnl + (size_t)j * N_ * C_;
            sim_mfma_k<<<dim3(64, 64), 256, 0, stream>>>(
                Ahi, Alo, Bhi, Blo, E, ET, rpMax, rpArg, rpSum, cpMax, cpArg, cpSum);
            merge_k<<<dim3(64, 2), 256, 0, stream>>>(
                rpMax, rpArg, rpSum, cpMax, cpArg, cpSum, rowArg, rowSum, colArg, colSum);
            int pid0 = i * 4 + j, pid1 = j * 4 + i;
            p2_k<<<dim3(4, 64, 2), 256, 0, stream>>>(
                E, ET, sfT, i, j, rowArg, colArg, rowSum, colSum,
                R + (size_t)i * N_ * C_, R + (size_t)j * N_ * C_,
                relwt, pid0, pid1, pairSq, pairCnt);
        }
    }
    final_k<<<1, 64, 0, stream>>>(pairSq, pairCnt, out);
}